// Round 1
// baseline (218.234 us; speedup 1.0000x reference)
//
#include <hip/hip_runtime.h>
#include <math.h>

#define HDIM 768
#define NSAMP 512
#define NLOG 513            // 1 target + 512 noise
#define TPB 256

// One block per token n. Stages h[n] in LDS, computes 513 gathered dot
// products (wave-parallel: 3 x float4 per lane, 64-lane shuffle reduce),
// then block log-softmax + per-token loss into ws.
__global__ __launch_bounds__(TPB) void nce_token_kernel(
    const float* __restrict__ h, const float* __restrict__ W,
    const int* __restrict__ target, const int* __restrict__ noise,
    float* __restrict__ loss_per_token)
{
    const int n    = blockIdx.x;
    const int tid  = threadIdx.x;
    const int lane = tid & 63;
    const int wave = tid >> 6;

    __shared__ float  logits[NLOG];
    __shared__ float4 hsm[HDIM / 4];       // 192 float4 = 3 KB
    __shared__ float  red[4];
    __shared__ float  red2[4][2];

    // stage h[n] into LDS (coalesced float4)
    const float4* hrow = reinterpret_cast<const float4*>(h + (size_t)n * HDIM);
    if (tid < HDIM / 4) hsm[tid] = hrow[tid];
    __syncthreads();

    // each lane's slice of h: elements [lane*4 .. ], strided by 256 floats
    const float4 h0 = hsm[lane];
    const float4 h1 = hsm[lane + 64];
    const float4 h2 = hsm[lane + 128];

    const int* nrow = noise + (size_t)n * NSAMP;

    // each wave takes rows r = wave, wave+4, ...
    for (int r = wave; r < NLOG; r += 4) {
        const int row = (r == 0) ? target[n] : nrow[r - 1];
        const float4* wr = reinterpret_cast<const float4*>(W + (size_t)row * HDIM);
        const float4 w0 = wr[lane];
        const float4 w1 = wr[lane + 64];
        const float4 w2 = wr[lane + 128];
        float s;
        s  = h0.x * w0.x + h0.y * w0.y + h0.z * w0.z + h0.w * w0.w;
        s += h1.x * w1.x + h1.y * w1.y + h1.z * w1.z + h1.w * w1.w;
        s += h2.x * w2.x + h2.y * w2.y + h2.z * w2.z + h2.w * w2.w;
        #pragma unroll
        for (int off = 32; off; off >>= 1) s += __shfl_xor(s, off, 64);
        if (lane == 0) logits[r] = s;
    }
    __syncthreads();

    // ---- block log-softmax over 513 logits ----
    float lmax = -INFINITY;
    for (int r = tid; r < NLOG; r += TPB) lmax = fmaxf(lmax, logits[r]);
    #pragma unroll
    for (int off = 32; off; off >>= 1) lmax = fmaxf(lmax, __shfl_xor(lmax, off, 64));
    if (lane == 0) red[wave] = lmax;
    __syncthreads();
    lmax = fmaxf(fmaxf(red[0], red[1]), fmaxf(red[2], red[3]));

    float esum = 0.f, lsum = 0.f;
    for (int r = tid; r < NLOG; r += TPB) {
        const float l = logits[r];
        esum += __expf(l - lmax);
        if (r > 0) lsum += l;          // sum of noise logits only
    }
    #pragma unroll
    for (int off = 32; off; off >>= 1) {
        esum += __shfl_xor(esum, off, 64);
        lsum += __shfl_xor(lsum, off, 64);
    }
    if (lane == 0) { red2[wave][0] = esum; red2[wave][1] = lsum; }
    __syncthreads();

    if (tid == 0) {
        esum = red2[0][0] + red2[1][0] + red2[2][0] + red2[3][0];
        lsum = red2[0][1] + red2[1][1] + red2[2][1] + red2[3][1];
        const float lse  = lmax + logf(esum);
        const float l0   = logits[0];
        // -0.9*(l0-lse) - (0.1/512)*sum_{s>=1}(l_s - lse)
        const float loss = -0.9f * (l0 - lse)
                         - (0.1f / 512.f) * (lsum - 512.f * lse);
        loss_per_token[n] = loss;
    }
}

// Single-block deterministic mean of N per-token losses.
__global__ __launch_bounds__(TPB) void reduce_mean_kernel(
    const float* __restrict__ x, float* __restrict__ out, int n)
{
    const int tid = threadIdx.x;
    float s = 0.f;
    for (int i = tid; i < n; i += TPB) s += x[i];
    #pragma unroll
    for (int off = 32; off; off >>= 1) s += __shfl_xor(s, off, 64);
    __shared__ float red[4];
    if ((tid & 63) == 0) red[tid >> 6] = s;
    __syncthreads();
    if (tid == 0) out[0] = (red[0] + red[1] + red[2] + red[3]) / (float)n;
}

extern "C" void kernel_launch(void* const* d_in, const int* in_sizes, int n_in,
                              void* d_out, int out_size, void* d_ws, size_t ws_size,
                              hipStream_t stream)
{
    const float* h      = (const float*)d_in[0];   // [N, 768] fp32
    const float* W      = (const float*)d_in[1];   // [50257, 768] fp32
    const int*   target = (const int*)d_in[2];     // [N] int32
    const int*   noise  = (const int*)d_in[3];     // [N, 512] int32
    float*       out    = (float*)d_out;           // scalar loss
    float*       ws     = (float*)d_ws;            // >= N floats scratch

    const int N = in_sizes[2];                     // 1024 tokens

    nce_token_kernel<<<N, TPB, 0, stream>>>(h, W, target, noise, ws);
    reduce_mean_kernel<<<1, TPB, 0, stream>>>(ws, out, N);
}